// Round 5
// baseline (511.438 us; speedup 1.0000x reference)
//
#include <hip/hip_runtime.h>

// IGCN forward, CSR formulation, round 5.
//  - ONE CSR (from adj edges) serves feat-SpMM (+bias, degF=degA+1) and all
//    adj-SpMMs; built reading each interaction pair once.
//  - CSR build pinned to PHYSICAL XCD: range = s_getreg(HW_REG_XCC_ID),
//    persistent blocks pull chunks from a per-XCD atomic counter. Each
//    range's scatter window (~1MB colA slice + 50KB cur slice) is then
//    written by exactly one XCD's L2 -> write-back ~once per line.
//    Pair streams use non-temporal loads so they don't evict the window.
//  - Scaled-state trick: buffers hold y~ = rsD[row]*y[row]; adjacency SpMM
//    inner loop is a pure gather-sum, final scale 1/deg; gathered rows
//    un-scale by sqrt(deg) (deg=0 -> scale 1 both ways, exact).
//  - SpMM: wave = 4 edge-slots x 16 dim-lanes, unroll 2 -> 8 gathers in flight.

constexpr int kNU = 60000;
constexpr int kNI = 40000;
constexpr int kN  = 100000;
constexpr int kB  = 4096;
constexpr int kNRange = 8, kRangeSz = 12500;   // 8 * 12500 = 100000
constexpr int kNChunk = 256;                   // chunks per range

using iv4 = __attribute__((ext_vector_type(4))) int;

__device__ __forceinline__ int xcd_id() {
  // HW_REG_XCC_ID = 20 (gfx940+). simm16 = id | offset<<6 | (width-1)<<11.
  // Read full 32b, mask to 8 XCDs. [measured working on MI355X: learn_hip m09]
  return __builtin_amdgcn_s_getreg(20 | (31 << 11)) & 7;
}

// ---------------- CSR build (persistent, XCD-pinned) ----------------
__global__ void count_xcd(const iv4* __restrict__ u4, const iv4* __restrict__ i4,
                          int nV, int* __restrict__ deg, int* __restrict__ ctr) {
  int xcd = xcd_id();
  int lo = xcd * kRangeSz, hi = lo + kRangeSz;
  int chunkLen = (nV + kNChunk - 1) / kNChunk;
  __shared__ int sC;
  for (;;) {
    if (threadIdx.x == 0) sC = atomicAdd(&ctr[xcd], 1);
    __syncthreads();
    int c = sC;
    __syncthreads();
    if (c >= kNChunk) break;
    int p0 = c * chunkLen, p1 = min(nV, p0 + chunkLen);
    for (int p = p0 + (int)threadIdx.x; p < p1; p += 256) {
      iv4 uu = __builtin_nontemporal_load(&u4[p]);
      iv4 ii = __builtin_nontemporal_load(&i4[p]);
      #pragma unroll
      for (int k = 0; k < 4; ++k) {
        int a = uu[k], b = ii[k];
        if (a >= lo && a < hi) atomicAdd(&deg[a], 1);
        if (b >= lo && b < hi) atomicAdd(&deg[b], 1);
      }
    }
  }
}

__global__ void scatter_xcd(const iv4* __restrict__ u4, const iv4* __restrict__ i4,
                            int nV, int* __restrict__ cur, int* __restrict__ colsOut,
                            int* __restrict__ ctr) {
  int xcd = xcd_id();
  int lo = xcd * kRangeSz, hi = lo + kRangeSz;
  int chunkLen = (nV + kNChunk - 1) / kNChunk;
  __shared__ int sC;
  for (;;) {
    if (threadIdx.x == 0) sC = atomicAdd(&ctr[xcd], 1);
    __syncthreads();
    int c = sC;
    __syncthreads();
    if (c >= kNChunk) break;
    int p0 = c * chunkLen, p1 = min(nV, p0 + chunkLen);
    for (int p = p0 + (int)threadIdx.x; p < p1; p += 256) {
      iv4 uu = __builtin_nontemporal_load(&u4[p]);
      iv4 ii = __builtin_nontemporal_load(&i4[p]);
      #pragma unroll
      for (int k = 0; k < 4; ++k) {
        int a = uu[k], b = ii[k];
        if (a >= lo && a < hi) colsOut[atomicAdd(&cur[a], 1)] = b;
        if (b >= lo && b < hi) colsOut[atomicAdd(&cur[b], 1)] = a;
      }
    }
  }
}

// ---------------- scan ----------------
constexpr int SCAN_T = 256, SCAN_E = 8, SCAN_CH = SCAN_T * SCAN_E;  // 2048

__global__ void scan_p1(const int* __restrict__ in, int n, int* __restrict__ bsum) {
  __shared__ int lds[SCAN_T];
  int t = threadIdx.x;
  int base = blockIdx.x * SCAN_CH + t * SCAN_E;
  int s = 0;
  #pragma unroll
  for (int k = 0; k < SCAN_E; ++k) { int i = base + k; if (i < n) s += in[i]; }
  lds[t] = s; __syncthreads();
  for (int off = SCAN_T / 2; off; off >>= 1) {
    if (t < off) lds[t] += lds[t + off];
    __syncthreads();
  }
  if (t == 0) bsum[blockIdx.x] = lds[0];
}

__global__ void scan_p2(int* bsum, int nb) {
  if (threadIdx.x == 0 && blockIdx.x == 0) {
    int run = 0;
    for (int i = 0; i < nb; ++i) { int v = bsum[i]; bsum[i] = run; run += v; }
  }
}

__global__ void scan_p3(const int* __restrict__ in, int n, int ntot,
                        const int* __restrict__ bsum,
                        int* __restrict__ out, int* __restrict__ cur) {
  __shared__ int lds[SCAN_T];
  int t = threadIdx.x;
  int base = blockIdx.x * SCAN_CH + t * SCAN_E;
  int v[SCAN_E]; int s = 0;
  #pragma unroll
  for (int k = 0; k < SCAN_E; ++k) { int i = base + k; v[k] = (i < n) ? in[i] : 0; s += v[k]; }
  lds[t] = s; __syncthreads();
  for (int off = 1; off < SCAN_T; off <<= 1) {
    int x = (t >= off) ? lds[t - off] : 0;
    __syncthreads();
    lds[t] += x;
    __syncthreads();
  }
  int pre = lds[t] - s + bsum[blockIdx.x];
  #pragma unroll
  for (int k = 0; k < SCAN_E; ++k) {
    int i = base + k;
    if (i < n) { out[i] = pre; cur[i] = pre; pre += v[k]; }
  }
  if (blockIdx.x == 0 && t == 0) out[n] = ntot;
}

__global__ void make_rsd(const int* __restrict__ deg, float* __restrict__ rsDg, int n) {
  int i = blockIdx.x * blockDim.x + threadIdx.x;
  if (i < n) { int d = deg[i]; rsDg[i] = d > 0 ? rsqrtf((float)d) : 1.f; }
}

// ---------------- SpMM: wave = 4 edge-slots x 16 dim-lanes, unroll 2 --------
// feat: out~[row] = rsDg[row] * (sum emb[c] + emb[bias]) / (deg+1)
__global__ void spmm_feat_half(const int* __restrict__ rs, const int* __restrict__ cols,
                               const float4* __restrict__ emb4, float4* __restrict__ out4,
                               const float* __restrict__ rsDg,
                               int row0, int nrows, int biasIdx) {
  int r = blockIdx.x * 4 + (threadIdx.x >> 6);
  if (r >= nrows) return;
  int row = row0 + r;
  int lane = threadIdx.x & 63, g = lane >> 4, q = lane & 15;
  int s = rs[row], e = rs[row + 1];
  float4 a = {0.f, 0.f, 0.f, 0.f}, b = {0.f, 0.f, 0.f, 0.f};
  int j = s + g;
  for (; j + 4 < e; j += 8) {
    int c0 = cols[j], c1 = cols[j + 4];
    float4 v0 = emb4[(long)c0 * 16 + q];
    float4 v1 = emb4[(long)c1 * 16 + q];
    a.x += v0.x; a.y += v0.y; a.z += v0.z; a.w += v0.w;
    b.x += v1.x; b.y += v1.y; b.z += v1.z; b.w += v1.w;
  }
  if (j < e) {
    int c = cols[j];
    float4 v = emb4[(long)c * 16 + q];
    a.x += v.x; a.y += v.y; a.z += v.z; a.w += v.w;
  }
  a.x += b.x; a.y += b.y; a.z += b.z; a.w += b.w;
  #pragma unroll
  for (int m = 16; m <= 32; m <<= 1) {
    a.x += __shfl_xor(a.x, m, 64);
    a.y += __shfl_xor(a.y, m, 64);
    a.z += __shfl_xor(a.z, m, 64);
    a.w += __shfl_xor(a.w, m, 64);
  }
  if (g == 0) {
    float4 bv = emb4[(long)biasIdx * 16 + q];
    float sc = rsDg[row] / (float)(e - s + 1);
    a.x = (a.x + bv.x) * sc; a.y = (a.y + bv.y) * sc;
    a.z = (a.z + bv.z) * sc; a.w = (a.w + bv.w) * sc;
    out4[(long)r * 16 + q] = a;
  }
}

// adj: out~[row] = (1/deg[row]) * sum in~[c]   (pure gather-sum inner loop)
__global__ void spmm_adj_half(const int* __restrict__ rs, const int* __restrict__ cols,
                              const float* __restrict__ rsDg, const float4* __restrict__ in4,
                              float4* __restrict__ out4, int row0, int nrows, int colOff) {
  int r = blockIdx.x * 4 + (threadIdx.x >> 6);
  if (r >= nrows) return;
  int row = row0 + r;
  int lane = threadIdx.x & 63, g = lane >> 4, q = lane & 15;
  int s = rs[row], e = rs[row + 1];
  float4 a = {0.f, 0.f, 0.f, 0.f}, b = {0.f, 0.f, 0.f, 0.f};
  int j = s + g;
  for (; j + 4 < e; j += 8) {
    int c0 = cols[j], c1 = cols[j + 4];
    float4 v0 = in4[(long)(c0 - colOff) * 16 + q];
    float4 v1 = in4[(long)(c1 - colOff) * 16 + q];
    a.x += v0.x; a.y += v0.y; a.z += v0.z; a.w += v0.w;
    b.x += v1.x; b.y += v1.y; b.z += v1.z; b.w += v1.w;
  }
  if (j < e) {
    int c = cols[j];
    float4 v = in4[(long)(c - colOff) * 16 + q];
    a.x += v.x; a.y += v.y; a.z += v.z; a.w += v.w;
  }
  a.x += b.x; a.y += b.y; a.z += b.z; a.w += b.w;
  #pragma unroll
  for (int m = 16; m <= 32; m <<= 1) {
    a.x += __shfl_xor(a.x, m, 64);
    a.y += __shfl_xor(a.y, m, 64);
    a.z += __shfl_xor(a.z, m, 64);
    a.w += __shfl_xor(a.w, m, 64);
  }
  if (g == 0) {
    float w = rsDg[row]; w = w * w;   // = 1/deg (deg>0); empty row -> sum 0
    a.x *= w; a.y *= w; a.z *= w; a.w *= w;
    out4[(long)r * 16 + q] = a;
  }
}

// ---------------- gathered-row accumulation (un-scale by sqrt(deg)) ---------
__global__ void acc_gather(const float4* __restrict__ bufU, const float4* __restrict__ bufI,
                           const int* __restrict__ deg,
                           const int* __restrict__ users, const int* __restrict__ pos,
                           const int* __restrict__ neg, float4* __restrict__ out, int add) {
  int g = blockIdx.x * blockDim.x + threadIdx.x;
  if (g >= 3 * kB * 16) return;
  int slot = g >> 4, q = g & 15;
  int which = slot >> 12, b = slot & (kB - 1);
  int node = which == 0 ? users[b] : (which == 1 ? pos[b] + kNU : neg[b] + kNU);
  float4 v = (node < kNU) ? bufU[(long)node * 16 + q] : bufI[(long)(node - kNU) * 16 + q];
  float sq = sqrtf((float)max(deg[node], 1));   // y = y~ * sqrt(deg); deg=0 -> 1
  v.x *= sq; v.y *= sq; v.z *= sq; v.w *= sq;
  if (add) { float4 o = out[g]; v.x += o.x; v.y += o.y; v.z += o.z; v.w += o.w; }
  out[g] = v;
}

// layer 3 restricted to gathered rows + /4 + per-row L2 partial
__global__ void layer3_fin(const int* __restrict__ rs, const int* __restrict__ cols,
                           const float* __restrict__ rsDg,
                           const float4* __restrict__ bufU, const float4* __restrict__ bufI,
                           const int* __restrict__ users, const int* __restrict__ pos,
                           const int* __restrict__ neg,
                           float4* __restrict__ out, float* __restrict__ l2part) {
  int slot = blockIdx.x * 4 + (threadIdx.x >> 6);
  if (slot >= 3 * kB) return;
  int lane = threadIdx.x & 63, g = lane >> 4, q = lane & 15;
  int which = slot >> 12, b = slot & (kB - 1);
  int node = which == 0 ? users[b] : (which == 1 ? pos[b] + kNU : neg[b] + kNU);
  const float4* in; int coff;
  if (node < kNU) { in = bufI; coff = kNU; } else { in = bufU; coff = 0; }
  int s = rs[node], e = rs[node + 1];
  float4 a = {0.f, 0.f, 0.f, 0.f}, bb = {0.f, 0.f, 0.f, 0.f};
  int j = s + g;
  for (; j + 4 < e; j += 8) {
    int c0 = cols[j], c1 = cols[j + 4];
    float4 v0 = in[(long)(c0 - coff) * 16 + q];
    float4 v1 = in[(long)(c1 - coff) * 16 + q];
    a.x += v0.x; a.y += v0.y; a.z += v0.z; a.w += v0.w;
    bb.x += v1.x; bb.y += v1.y; bb.z += v1.z; bb.w += v1.w;
  }
  if (j < e) {
    int c = cols[j];
    float4 v = in[(long)(c - coff) * 16 + q];
    a.x += v.x; a.y += v.y; a.z += v.z; a.w += v.w;
  }
  a.x += bb.x; a.y += bb.y; a.z += bb.z; a.w += bb.w;
  #pragma unroll
  for (int m = 16; m <= 32; m <<= 1) {
    a.x += __shfl_xor(a.x, m, 64);
    a.y += __shfl_xor(a.y, m, 64);
    a.z += __shfl_xor(a.z, m, 64);
    a.w += __shfl_xor(a.w, m, 64);
  }
  float sr = rsDg[node];      // y3 = rsDg * sum(in~)
  float4 o = out[(long)slot * 16 + q];
  float rx = (o.x + a.x * sr) * 0.25f;
  float ry = (o.y + a.y * sr) * 0.25f;
  float rz = (o.z + a.z * sr) * 0.25f;
  float rw = (o.w + a.w * sr) * 0.25f;
  if (g == 0) { float4 rv = {rx, ry, rz, rw}; out[(long)slot * 16 + q] = rv; }
  float t = rx * rx + ry * ry + rz * rz + rw * rw;
  #pragma unroll
  for (int m = 1; m <= 8; m <<= 1) t += __shfl_xor(t, m, 64);
  if (lane == 0) l2part[slot] = t;
}

__global__ void l2_final(const float* __restrict__ l2part, float* __restrict__ outl2) {
  int b = blockIdx.x * blockDim.x + threadIdx.x;
  if (b < kB) outl2[b] = l2part[b] + l2part[kB + b] + l2part[2 * kB + b];
}

extern "C" void kernel_launch(void* const* d_in, const int* in_sizes, int n_in,
                              void* d_out, int out_size, void* d_ws, size_t ws_size,
                              hipStream_t stream) {
  const float* emb  = (const float*)d_in[0];
  const int*   arow = (const int*)d_in[3];
  const int*   users= (const int*)d_in[5];
  const int*   pos  = (const int*)d_in[6];
  const int*   neg  = (const int*)d_in[7];
  const int neA = in_sizes[3];              // 2,000,000
  const int nP  = neA / 2;                  // 1,000,000 pairs
  const int nV  = nP / 4;                   // int4 count
  const iv4* u4 = (const iv4*)arow;                 // users half
  const iv4* i4 = (const iv4*)(arow + nP);          // item-node half

  char* ws = (char*)d_ws;
  int*   degA   = (int*)(ws + 0);           // 400,000
  int*   rsArr  = (int*)(ws + 400000);      // 400,004 (pad to 400128)
  int*   cur    = (int*)(ws + 800128);      // 400,000
  float* rsDg   = (float*)(ws + 1200128);   // 400,000
  float* l2part = (float*)(ws + 1600128);   // 49,152
  int*   bsum   = (int*)(ws + 1649280);     // 1,024
  int*   ctr    = (int*)(ws + 1650304);     // 64 (2x8 per-XCD chunk counters)
  int*   colA   = (int*)(ws + 1650368);     // 8,000,000
  float* bufU   = (float*)(ws + 9650368);   // 15,360,000
  float* bufI0  = (float*)(ws + 25010368);  // 10,240,000
  float* bufI1  = (float*)(ws + 35250368);  // 10,240,000 -> end 45,490,368

  float* out = (float*)d_out;
  const int NB = (kN + SCAN_CH - 1) / SCAN_CH;  // 49

  hipMemsetAsync(degA, 0, 400000, stream);
  hipMemsetAsync(ctr, 0, 64, stream);
  count_xcd<<<2048, 256, 0, stream>>>(u4, i4, nV, degA, ctr);
  scan_p1<<<NB, SCAN_T, 0, stream>>>(degA, kN, bsum);
  scan_p2<<<1, 64, 0, stream>>>(bsum, NB);
  scan_p3<<<NB, SCAN_T, 0, stream>>>(degA, kN, neA, bsum, rsArr, cur);
  make_rsd<<<(kN + 255) / 256, 256, 0, stream>>>(degA, rsDg, kN);
  scatter_xcd<<<2048, 256, 0, stream>>>(u4, i4, nV, cur, colA, ctr + 8);

  // feature SpMM -> scaled state y~0
  spmm_feat_half<<<(kNU + 3) / 4, 256, 0, stream>>>(rsArr, colA, (const float4*)emb,
                                                    (float4*)bufU, rsDg, 0, kNU, 100000);
  spmm_feat_half<<<(kNI + 3) / 4, 256, 0, stream>>>(rsArr, colA, (const float4*)emb,
                                                    (float4*)bufI0, rsDg, kNU, kNI, 100001);
  acc_gather<<<(3 * kB * 16 + 255) / 256, 256, 0, stream>>>((const float4*)bufU,
      (const float4*)bufI0, degA, users, pos, neg, (float4*)out, 0);

  // layer 1: items from U, then users from I0 (bufU in place)
  spmm_adj_half<<<(kNI + 3) / 4, 256, 0, stream>>>(rsArr, colA, rsDg, (const float4*)bufU,
                                                   (float4*)bufI1, kNU, kNI, 0);
  spmm_adj_half<<<(kNU + 3) / 4, 256, 0, stream>>>(rsArr, colA, rsDg, (const float4*)bufI0,
                                                   (float4*)bufU, 0, kNU, kNU);
  acc_gather<<<(3 * kB * 16 + 255) / 256, 256, 0, stream>>>((const float4*)bufU,
      (const float4*)bufI1, degA, users, pos, neg, (float4*)out, 1);

  // layer 2
  spmm_adj_half<<<(kNI + 3) / 4, 256, 0, stream>>>(rsArr, colA, rsDg, (const float4*)bufU,
                                                   (float4*)bufI0, kNU, kNI, 0);
  spmm_adj_half<<<(kNU + 3) / 4, 256, 0, stream>>>(rsArr, colA, rsDg, (const float4*)bufI1,
                                                   (float4*)bufU, 0, kNU, kNU);
  acc_gather<<<(3 * kB * 16 + 255) / 256, 256, 0, stream>>>((const float4*)bufU,
      (const float4*)bufI0, degA, users, pos, neg, (float4*)out, 1);

  // layer 3 restricted + epilogue
  layer3_fin<<<(3 * kB + 3) / 4, 256, 0, stream>>>(rsArr, colA, rsDg, (const float4*)bufU,
                                                   (const float4*)bufI0, users, pos, neg,
                                                   (float4*)out, l2part);
  l2_final<<<(kB + 255) / 256, 256, 0, stream>>>(l2part, out + 3 * kB * 64);
}

// Round 6
// 511.066 us; speedup vs baseline: 1.0007x; 1.0007x over previous
//
#include <hip/hip_runtime.h>

// IGCN forward, CSR formulation, round 6.
//  - ONE CSR (from adj edges) serves feat-SpMM (+bias, degF=degA+1) and all
//    adj-SpMMs; built reading each interaction pair once.
//  - CSR build pinned to PHYSICAL XCD (s_getreg XCC_ID), persistent blocks
//    pull chunks from a per-XCD counter. NEW this round: deg/cur atomics are
//    WORKGROUP-SCOPE (__hip_atomic_fetch_add) -> execute in the local XCD L2
//    instead of writing through to the device coherence point. Correct
//    because pinning makes each deg/cur address single-XCD, and end-of-kernel
//    agent release flushes L2 for the next kernel. Ranges are 12512 rows so
//    range boundaries are 64B-line-aligned.
//  - Scaled-state trick: buffers hold y~ = rsD[row]*y[row]; adjacency SpMM
//    inner loop is a pure gather-sum, final scale 1/deg; gathered rows
//    un-scale by sqrt(deg) (deg=0 -> scale 1 both ways, exact).
//  - SpMM: wave = 4 edge-slots x 16 dim-lanes, unroll 2 -> 8 gathers in flight.

constexpr int kNU = 60000;
constexpr int kNI = 40000;
constexpr int kN  = 100000;
constexpr int kB  = 4096;
constexpr int kRangeSz = 12512;               // 64B-aligned (12512*4 = 782*64)
constexpr int kNChunk = 256;                  // chunks per range

using iv4 = __attribute__((ext_vector_type(4))) int;

__device__ __forceinline__ int xcd_id() {
  // HW_REG_XCC_ID = 20 (gfx940+). simm16 = id | offset<<6 | (width-1)<<11.
  return __builtin_amdgcn_s_getreg(20 | (31 << 11)) & 7;
}

__device__ __forceinline__ int atom_inc_local(int* p) {
  // XCD-L2-local atomic (workgroup scope): no device-coherence write-through.
  return __hip_atomic_fetch_add(p, 1, __ATOMIC_RELAXED, __HIP_MEMORY_SCOPE_WORKGROUP);
}

// ---------------- CSR build (persistent, XCD-pinned, local atomics) ---------
__global__ void count_xcd(const iv4* __restrict__ u4, const iv4* __restrict__ i4,
                          int nV, int* __restrict__ deg, int* __restrict__ ctr) {
  int xcd = xcd_id();
  int lo = xcd * kRangeSz, hi = min(lo + kRangeSz, kN);
  int chunkLen = (nV + kNChunk - 1) / kNChunk;
  __shared__ int sC;
  for (;;) {
    if (threadIdx.x == 0) sC = atomicAdd(&ctr[xcd], 1);
    __syncthreads();
    int c = sC;
    __syncthreads();
    if (c >= kNChunk) break;
    int p0 = c * chunkLen, p1 = min(nV, p0 + chunkLen);
    for (int p = p0 + (int)threadIdx.x; p < p1; p += 256) {
      iv4 uu = __builtin_nontemporal_load(&u4[p]);
      iv4 ii = __builtin_nontemporal_load(&i4[p]);
      #pragma unroll
      for (int k = 0; k < 4; ++k) {
        int a = uu[k], b = ii[k];
        if (a >= lo && a < hi) atom_inc_local(&deg[a]);
        if (b >= lo && b < hi) atom_inc_local(&deg[b]);
      }
    }
  }
}

__global__ void scatter_xcd(const iv4* __restrict__ u4, const iv4* __restrict__ i4,
                            int nV, int* __restrict__ cur, int* __restrict__ colsOut,
                            int* __restrict__ ctr) {
  int xcd = xcd_id();
  int lo = xcd * kRangeSz, hi = min(lo + kRangeSz, kN);
  int chunkLen = (nV + kNChunk - 1) / kNChunk;
  __shared__ int sC;
  for (;;) {
    if (threadIdx.x == 0) sC = atomicAdd(&ctr[xcd], 1);
    __syncthreads();
    int c = sC;
    __syncthreads();
    if (c >= kNChunk) break;
    int p0 = c * chunkLen, p1 = min(nV, p0 + chunkLen);
    for (int p = p0 + (int)threadIdx.x; p < p1; p += 256) {
      iv4 uu = __builtin_nontemporal_load(&u4[p]);
      iv4 ii = __builtin_nontemporal_load(&i4[p]);
      #pragma unroll
      for (int k = 0; k < 4; ++k) {
        int a = uu[k], b = ii[k];
        if (a >= lo && a < hi) colsOut[atom_inc_local(&cur[a])] = b;
        if (b >= lo && b < hi) colsOut[atom_inc_local(&cur[b])] = a;
      }
    }
  }
}

// ---------------- scan ----------------
constexpr int SCAN_T = 256, SCAN_E = 8, SCAN_CH = SCAN_T * SCAN_E;  // 2048

__global__ void scan_p1(const int* __restrict__ in, int n, int* __restrict__ bsum) {
  __shared__ int lds[SCAN_T];
  int t = threadIdx.x;
  int base = blockIdx.x * SCAN_CH + t * SCAN_E;
  int s = 0;
  #pragma unroll
  for (int k = 0; k < SCAN_E; ++k) { int i = base + k; if (i < n) s += in[i]; }
  lds[t] = s; __syncthreads();
  for (int off = SCAN_T / 2; off; off >>= 1) {
    if (t < off) lds[t] += lds[t + off];
    __syncthreads();
  }
  if (t == 0) bsum[blockIdx.x] = lds[0];
}

__global__ void scan_p2(int* bsum, int nb) {
  if (threadIdx.x == 0 && blockIdx.x == 0) {
    int run = 0;
    for (int i = 0; i < nb; ++i) { int v = bsum[i]; bsum[i] = run; run += v; }
  }
}

__global__ void scan_p3(const int* __restrict__ in, int n, int ntot,
                        const int* __restrict__ bsum,
                        int* __restrict__ out, int* __restrict__ cur) {
  __shared__ int lds[SCAN_T];
  int t = threadIdx.x;
  int base = blockIdx.x * SCAN_CH + t * SCAN_E;
  int v[SCAN_E]; int s = 0;
  #pragma unroll
  for (int k = 0; k < SCAN_E; ++k) { int i = base + k; v[k] = (i < n) ? in[i] : 0; s += v[k]; }
  lds[t] = s; __syncthreads();
  for (int off = 1; off < SCAN_T; off <<= 1) {
    int x = (t >= off) ? lds[t - off] : 0;
    __syncthreads();
    lds[t] += x;
    __syncthreads();
  }
  int pre = lds[t] - s + bsum[blockIdx.x];
  #pragma unroll
  for (int k = 0; k < SCAN_E; ++k) {
    int i = base + k;
    if (i < n) { out[i] = pre; cur[i] = pre; pre += v[k]; }
  }
  if (blockIdx.x == 0 && t == 0) out[n] = ntot;
}

__global__ void make_rsd(const int* __restrict__ deg, float* __restrict__ rsDg, int n) {
  int i = blockIdx.x * blockDim.x + threadIdx.x;
  if (i < n) { int d = deg[i]; rsDg[i] = d > 0 ? rsqrtf((float)d) : 1.f; }
}

// ---------------- SpMM: wave = 4 edge-slots x 16 dim-lanes, unroll 2 --------
// feat: out~[row] = rsDg[row] * (sum emb[c] + emb[bias]) / (deg+1)
__global__ void spmm_feat_half(const int* __restrict__ rs, const int* __restrict__ cols,
                               const float4* __restrict__ emb4, float4* __restrict__ out4,
                               const float* __restrict__ rsDg,
                               int row0, int nrows, int biasIdx) {
  int r = blockIdx.x * 4 + (threadIdx.x >> 6);
  if (r >= nrows) return;
  int row = row0 + r;
  int lane = threadIdx.x & 63, g = lane >> 4, q = lane & 15;
  int s = rs[row], e = rs[row + 1];
  float4 a = {0.f, 0.f, 0.f, 0.f}, b = {0.f, 0.f, 0.f, 0.f};
  int j = s + g;
  for (; j + 4 < e; j += 8) {
    int c0 = cols[j], c1 = cols[j + 4];
    float4 v0 = emb4[(long)c0 * 16 + q];
    float4 v1 = emb4[(long)c1 * 16 + q];
    a.x += v0.x; a.y += v0.y; a.z += v0.z; a.w += v0.w;
    b.x += v1.x; b.y += v1.y; b.z += v1.z; b.w += v1.w;
  }
  if (j < e) {
    int c = cols[j];
    float4 v = emb4[(long)c * 16 + q];
    a.x += v.x; a.y += v.y; a.z += v.z; a.w += v.w;
  }
  a.x += b.x; a.y += b.y; a.z += b.z; a.w += b.w;
  #pragma unroll
  for (int m = 16; m <= 32; m <<= 1) {
    a.x += __shfl_xor(a.x, m, 64);
    a.y += __shfl_xor(a.y, m, 64);
    a.z += __shfl_xor(a.z, m, 64);
    a.w += __shfl_xor(a.w, m, 64);
  }
  if (g == 0) {
    float4 bv = emb4[(long)biasIdx * 16 + q];
    float sc = rsDg[row] / (float)(e - s + 1);
    a.x = (a.x + bv.x) * sc; a.y = (a.y + bv.y) * sc;
    a.z = (a.z + bv.z) * sc; a.w = (a.w + bv.w) * sc;
    out4[(long)r * 16 + q] = a;
  }
}

// adj: out~[row] = (1/deg[row]) * sum in~[c]   (pure gather-sum inner loop)
__global__ void spmm_adj_half(const int* __restrict__ rs, const int* __restrict__ cols,
                              const float* __restrict__ rsDg, const float4* __restrict__ in4,
                              float4* __restrict__ out4, int row0, int nrows, int colOff) {
  int r = blockIdx.x * 4 + (threadIdx.x >> 6);
  if (r >= nrows) return;
  int row = row0 + r;
  int lane = threadIdx.x & 63, g = lane >> 4, q = lane & 15;
  int s = rs[row], e = rs[row + 1];
  float4 a = {0.f, 0.f, 0.f, 0.f}, b = {0.f, 0.f, 0.f, 0.f};
  int j = s + g;
  for (; j + 4 < e; j += 8) {
    int c0 = cols[j], c1 = cols[j + 4];
    float4 v0 = in4[(long)(c0 - colOff) * 16 + q];
    float4 v1 = in4[(long)(c1 - colOff) * 16 + q];
    a.x += v0.x; a.y += v0.y; a.z += v0.z; a.w += v0.w;
    b.x += v1.x; b.y += v1.y; b.z += v1.z; b.w += v1.w;
  }
  if (j < e) {
    int c = cols[j];
    float4 v = in4[(long)(c - colOff) * 16 + q];
    a.x += v.x; a.y += v.y; a.z += v.z; a.w += v.w;
  }
  a.x += b.x; a.y += b.y; a.z += b.z; a.w += b.w;
  #pragma unroll
  for (int m = 16; m <= 32; m <<= 1) {
    a.x += __shfl_xor(a.x, m, 64);
    a.y += __shfl_xor(a.y, m, 64);
    a.z += __shfl_xor(a.z, m, 64);
    a.w += __shfl_xor(a.w, m, 64);
  }
  if (g == 0) {
    float w = rsDg[row]; w = w * w;   // = 1/deg (deg>0); empty row -> sum 0
    a.x *= w; a.y *= w; a.z *= w; a.w *= w;
    out4[(long)r * 16 + q] = a;
  }
}

// ---------------- gathered-row accumulation (un-scale by sqrt(deg)) ---------
__global__ void acc_gather(const float4* __restrict__ bufU, const float4* __restrict__ bufI,
                           const int* __restrict__ deg,
                           const int* __restrict__ users, const int* __restrict__ pos,
                           const int* __restrict__ neg, float4* __restrict__ out, int add) {
  int g = blockIdx.x * blockDim.x + threadIdx.x;
  if (g >= 3 * kB * 16) return;
  int slot = g >> 4, q = g & 15;
  int which = slot >> 12, b = slot & (kB - 1);
  int node = which == 0 ? users[b] : (which == 1 ? pos[b] + kNU : neg[b] + kNU);
  float4 v = (node < kNU) ? bufU[(long)node * 16 + q] : bufI[(long)(node - kNU) * 16 + q];
  float sq = sqrtf((float)max(deg[node], 1));   // y = y~ * sqrt(deg); deg=0 -> 1
  v.x *= sq; v.y *= sq; v.z *= sq; v.w *= sq;
  if (add) { float4 o = out[g]; v.x += o.x; v.y += o.y; v.z += o.z; v.w += o.w; }
  out[g] = v;
}

// layer 3 restricted to gathered rows + /4 + per-row L2 partial
__global__ void layer3_fin(const int* __restrict__ rs, const int* __restrict__ cols,
                           const float* __restrict__ rsDg,
                           const float4* __restrict__ bufU, const float4* __restrict__ bufI,
                           const int* __restrict__ users, const int* __restrict__ pos,
                           const int* __restrict__ neg,
                           float4* __restrict__ out, float* __restrict__ l2part) {
  int slot = blockIdx.x * 4 + (threadIdx.x >> 6);
  if (slot >= 3 * kB) return;
  int lane = threadIdx.x & 63, g = lane >> 4, q = lane & 15;
  int which = slot >> 12, b = slot & (kB - 1);
  int node = which == 0 ? users[b] : (which == 1 ? pos[b] + kNU : neg[b] + kNU);
  const float4* in; int coff;
  if (node < kNU) { in = bufI; coff = kNU; } else { in = bufU; coff = 0; }
  int s = rs[node], e = rs[node + 1];
  float4 a = {0.f, 0.f, 0.f, 0.f}, bb = {0.f, 0.f, 0.f, 0.f};
  int j = s + g;
  for (; j + 4 < e; j += 8) {
    int c0 = cols[j], c1 = cols[j + 4];
    float4 v0 = in[(long)(c0 - coff) * 16 + q];
    float4 v1 = in[(long)(c1 - coff) * 16 + q];
    a.x += v0.x; a.y += v0.y; a.z += v0.z; a.w += v0.w;
    bb.x += v1.x; bb.y += v1.y; bb.z += v1.z; bb.w += v1.w;
  }
  if (j < e) {
    int c = cols[j];
    float4 v = in[(long)(c - coff) * 16 + q];
    a.x += v.x; a.y += v.y; a.z += v.z; a.w += v.w;
  }
  a.x += bb.x; a.y += bb.y; a.z += bb.z; a.w += bb.w;
  #pragma unroll
  for (int m = 16; m <= 32; m <<= 1) {
    a.x += __shfl_xor(a.x, m, 64);
    a.y += __shfl_xor(a.y, m, 64);
    a.z += __shfl_xor(a.z, m, 64);
    a.w += __shfl_xor(a.w, m, 64);
  }
  float sr = rsDg[node];      // y3 = rsDg * sum(in~)
  float4 o = out[(long)slot * 16 + q];
  float rx = (o.x + a.x * sr) * 0.25f;
  float ry = (o.y + a.y * sr) * 0.25f;
  float rz = (o.z + a.z * sr) * 0.25f;
  float rw = (o.w + a.w * sr) * 0.25f;
  if (g == 0) { float4 rv = {rx, ry, rz, rw}; out[(long)slot * 16 + q] = rv; }
  float t = rx * rx + ry * ry + rz * rz + rw * rw;
  #pragma unroll
  for (int m = 1; m <= 8; m <<= 1) t += __shfl_xor(t, m, 64);
  if (lane == 0) l2part[slot] = t;
}

__global__ void l2_final(const float* __restrict__ l2part, float* __restrict__ outl2) {
  int b = blockIdx.x * blockDim.x + threadIdx.x;
  if (b < kB) outl2[b] = l2part[b] + l2part[kB + b] + l2part[2 * kB + b];
}

extern "C" void kernel_launch(void* const* d_in, const int* in_sizes, int n_in,
                              void* d_out, int out_size, void* d_ws, size_t ws_size,
                              hipStream_t stream) {
  const float* emb  = (const float*)d_in[0];
  const int*   arow = (const int*)d_in[3];
  const int*   users= (const int*)d_in[5];
  const int*   pos  = (const int*)d_in[6];
  const int*   neg  = (const int*)d_in[7];
  const int neA = in_sizes[3];              // 2,000,000
  const int nP  = neA / 2;                  // 1,000,000 pairs
  const int nV  = nP / 4;                   // int4 count
  const iv4* u4 = (const iv4*)arow;                 // users half
  const iv4* i4 = (const iv4*)(arow + nP);          // item-node half

  char* ws = (char*)d_ws;
  int*   degA   = (int*)(ws + 0);           // 400,000
  int*   rsArr  = (int*)(ws + 400000);      // 400,004 (pad to 400128)
  int*   cur    = (int*)(ws + 800128);      // 400,000
  float* rsDg   = (float*)(ws + 1200128);   // 400,000
  float* l2part = (float*)(ws + 1600128);   // 49,152
  int*   bsum   = (int*)(ws + 1649280);     // 1,024
  int*   ctr    = (int*)(ws + 1650304);     // 64 (2x8 per-XCD chunk counters)
  int*   colA   = (int*)(ws + 1650368);     // 8,000,000
  float* bufU   = (float*)(ws + 9650368);   // 15,360,000
  float* bufI0  = (float*)(ws + 25010368);  // 10,240,000
  float* bufI1  = (float*)(ws + 35250368);  // 10,240,000 -> end 45,490,368

  float* out = (float*)d_out;
  const int NB = (kN + SCAN_CH - 1) / SCAN_CH;  // 49

  hipMemsetAsync(degA, 0, 400000, stream);
  hipMemsetAsync(ctr, 0, 64, stream);
  count_xcd<<<2048, 256, 0, stream>>>(u4, i4, nV, degA, ctr);
  scan_p1<<<NB, SCAN_T, 0, stream>>>(degA, kN, bsum);
  scan_p2<<<1, 64, 0, stream>>>(bsum, NB);
  scan_p3<<<NB, SCAN_T, 0, stream>>>(degA, kN, neA, bsum, rsArr, cur);
  make_rsd<<<(kN + 255) / 256, 256, 0, stream>>>(degA, rsDg, kN);
  scatter_xcd<<<2048, 256, 0, stream>>>(u4, i4, nV, cur, colA, ctr + 8);

  // feature SpMM -> scaled state y~0
  spmm_feat_half<<<(kNU + 3) / 4, 256, 0, stream>>>(rsArr, colA, (const float4*)emb,
                                                    (float4*)bufU, rsDg, 0, kNU, 100000);
  spmm_feat_half<<<(kNI + 3) / 4, 256, 0, stream>>>(rsArr, colA, (const float4*)emb,
                                                    (float4*)bufI0, rsDg, kNU, kNI, 100001);
  acc_gather<<<(3 * kB * 16 + 255) / 256, 256, 0, stream>>>((const float4*)bufU,
      (const float4*)bufI0, degA, users, pos, neg, (float4*)out, 0);

  // layer 1: items from U, then users from I0 (bufU in place)
  spmm_adj_half<<<(kNI + 3) / 4, 256, 0, stream>>>(rsArr, colA, rsDg, (const float4*)bufU,
                                                   (float4*)bufI1, kNU, kNI, 0);
  spmm_adj_half<<<(kNU + 3) / 4, 256, 0, stream>>>(rsArr, colA, rsDg, (const float4*)bufI0,
                                                   (float4*)bufU, 0, kNU, kNU);
  acc_gather<<<(3 * kB * 16 + 255) / 256, 256, 0, stream>>>((const float4*)bufU,
      (const float4*)bufI1, degA, users, pos, neg, (float4*)out, 1);

  // layer 2
  spmm_adj_half<<<(kNI + 3) / 4, 256, 0, stream>>>(rsArr, colA, rsDg, (const float4*)bufU,
                                                   (float4*)bufI0, kNU, kNI, 0);
  spmm_adj_half<<<(kNU + 3) / 4, 256, 0, stream>>>(rsArr, colA, rsDg, (const float4*)bufI1,
                                                   (float4*)bufU, 0, kNU, kNU);
  acc_gather<<<(3 * kB * 16 + 255) / 256, 256, 0, stream>>>((const float4*)bufU,
      (const float4*)bufI0, degA, users, pos, neg, (float4*)out, 1);

  // layer 3 restricted + epilogue
  layer3_fin<<<(3 * kB + 3) / 4, 256, 0, stream>>>(rsArr, colA, rsDg, (const float4*)bufU,
                                                   (const float4*)bufI0, users, pos, neg,
                                                   (float4*)out, l2part);
  l2_final<<<(kB + 255) / 256, 256, 0, stream>>>(l2part, out + 3 * kB * 64);
}